// Round 1
// baseline (4000.515 us; speedup 1.0000x reference)
//
#include <hip/hip_runtime.h>
#include <math.h>

// Problem constants: B=8192, S=2TX=64, F=65, HID=128, 3H=384, DIMZ=64, DIRS=2
// GD_STEP=1e-6 (two_step=2e-6), GD_ITERS=10, BN_EPS=1e-5

__device__ __forceinline__ void fma4(float4& c, float a, const float4 w) {
  c.x += a*w.x; c.y += a*w.y; c.z += a*w.z; c.w += a*w.w;
}
__device__ __forceinline__ float vget(const float4& v, int i) { return ((const float*)&v)[i]; }

// ---------------------------------------------------------------------------
// K1: per-batch feats = [HtH | Hty]  (B,64,65) + BN stat partials (spaced atomics)
// ---------------------------------------------------------------------------
__global__ __launch_bounds__(256) void k_feats(
    const float* __restrict__ Hm, const float* __restrict__ y,
    float* __restrict__ feats, float* __restrict__ bnacc)
{
  __shared__ __align__(16) float Hl[64][68];
  __shared__ float yl[64];
  __shared__ float s1[64], s2[64];
  const int b = blockIdx.x;
  const int tid = threadIdx.x;
  const float* Hb = Hm + (size_t)b*4096;
  for (int i = tid; i < 4096; i += 256) Hl[i>>6][i&63] = Hb[i];
  if (tid < 64) { yl[tid] = y[b*64+tid]; s1[tid] = 0.f; s2[tid] = 0.f; }
  __syncthreads();

  float* fb = feats + (size_t)b*4160;
  if (tid < 64) {                       // Hty column (f=64)
    float acc = 0.f;
    for (int r = 0; r < 64; ++r) acc += Hl[r][tid]*yl[r];
    fb[tid*65+64] = acc;
    atomicAdd(&s1[tid], acc);
    atomicAdd(&s2[tid], acc*acc);
  }
  // HtH: 4x4 register tile per thread
  const int tg = tid & 15, ug = tid >> 4;
  float4 acc[4];
  acc[0]=acc[1]=acc[2]=acc[3]=make_float4(0.f,0.f,0.f,0.f);
  for (int r = 0; r < 64; ++r) {
    const float4 tv = *(const float4*)&Hl[r][4*tg];
    const float4 uv = *(const float4*)&Hl[r][4*ug];
    #pragma unroll
    for (int tt=0;tt<4;++tt) fma4(acc[tt], vget(tv,tt), uv);
  }
  #pragma unroll
  for (int tt=0;tt<4;++tt) {
    const int t = 4*tg+tt;
    float sv=0.f, sq=0.f;
    #pragma unroll
    for (int uu=0;uu<4;++uu) {
      const float v = vget(acc[tt],uu);
      fb[t*65 + 4*ug + uu] = v;
      sv += v; sq += v*v;
    }
    // reduce over lanes sharing tg (lane, lane+16, lane+32, lane+48)
    sv += __shfl_down(sv,32); sq += __shfl_down(sq,32);
    sv += __shfl_down(sv,16); sq += __shfl_down(sq,16);
    if ((tid & 63) < 16) { atomicAdd(&s1[t], sv); atomicAdd(&s2[t], sq); }
  }
  __syncthreads();
  if (tid < 64) {
    atomicAdd(&bnacc[tid*16],      s1[tid]);   // spaced 64B to spread L2 slices
    atomicAdd(&bnacc[(64+tid)*16], s2[tid]);
  }
}

// ---------------------------------------------------------------------------
// K2a: BN finalize -> a[t]=gamma/sqrt(var+eps), c[t]=beta-mu*a
// ---------------------------------------------------------------------------
__global__ void k_bnfin(const float* __restrict__ bnacc, const float* __restrict__ gam,
                        const float* __restrict__ bet, float* __restrict__ bnac)
{
  const int t = threadIdx.x;
  if (t < 64) {
    const float inv = 1.f/532480.f;           // B*F = 8192*65
    const float mu  = bnacc[t*16]*inv;
    const float var = bnacc[(64+t)*16]*inv - mu*mu;
    const float a = gam[t]*rsqrtf(var + 1e-5f);
    bnac[t] = a;
    bnac[64+t] = bet[t] - mu*a;
  }
}

// ---------------------------------------------------------------------------
// K2b: weight transposes (k-major for float4 streaming) + wih row sums
// ---------------------------------------------------------------------------
__global__ __launch_bounds__(256) void k_prep(
    const float* __restrict__ wih, const float* __restrict__ whh,
    const float* __restrict__ Wz, const float* __restrict__ Wx,
    float* __restrict__ wiht, float* __restrict__ whht,
    float* __restrict__ wzt, float* __restrict__ wxt, float* __restrict__ rowsum)
{
  const int i = blockIdx.x*256 + threadIdx.x;
  if (i < 49920) { const int d=i/24960, r=i%24960, f=r/384, g=r%384;
                   wiht[i] = wih[d*24960 + g*65 + f]; }
  if (i < 98304) { const int d=i/49152, r=i%49152, j=r/384, g=r%384;
                   whht[i] = whh[d*49152 + g*128 + j]; }
  if (i < 16384) { const int d=i/8192, r=i%8192, j=r/64, z=r%64;
                   wzt[i] = Wz[z*256 + d*128 + j];
                   wxt[i] = Wx[z*256 + d*128 + j]; }
  if (i < 768)   { const int d=i/384, g=i%384; float s=0.f;
                   for (int f=0; f<65; ++f) s += wih[d*24960 + g*65 + f];
                   rowsum[i] = s; }
}

// ---------------------------------------------------------------------------
// K3: bidirectional GRU scan, fused BN affine + input transform + recurrent
//     matmul + gates + output projections (w_x stored per-dir; z0 in regs)
// One block = 64 batches x one direction. 512 threads.
// ---------------------------------------------------------------------------
__global__ __launch_bounds__(512) void k_scan(
    const float* __restrict__ feats, const float* __restrict__ xraw,
    const float* __restrict__ wiht, const float* __restrict__ whht,
    const float* __restrict__ wxtw, const float* __restrict__ wztw,
    const float* __restrict__ bih, const float* __restrict__ bhh,
    const float* __restrict__ rowsum, const float* __restrict__ bnac,
    float* __restrict__ wx_out, float* __restrict__ z0_out)
{
  __shared__ __align__(16) float Fl[65][68];   // a_s * feats[:,s,:]   [f][b]
  __shared__ __align__(16) float hl[128][68];  // hidden state         [j][b]
  __shared__ float RS[384], BI[384], BH[384];

  const int blk  = blockIdx.x;
  const int tile = blk >> 1, d = blk & 1;
  const int b0   = tile * 64;
  const int tid  = threadIdx.x;
  const int jg = tid & 31, bg = tid >> 5;          // gate-phase mapping
  const int wid = tid >> 6, lane = tid & 63;       // staging mapping
  const int pzg = tid & 15, pmat = (tid >> 4) & 1, pbg = tid >> 5;  // proj mapping

  const float* wihtd = wiht + d*24960;   // [k=f][g]
  const float* whhtd = whht + d*49152;   // [k=j2][g]
  const float* wxtd  = wxtw + d*8192;    // [k=j][z]
  const float* wztd  = wztw + d*8192;
  float* wxo = wx_out + (size_t)d * (8192ull*4096ull);
  float* z0o = z0_out + (size_t)d * (8192ull*64ull);

  for (int i = tid; i < 384; i += 512) {
    RS[i] = rowsum[d*384+i]; BI[i] = bih[d*384+i]; BH[i] = bhh[d*384+i];
  }
  for (int i = tid; i < 128*68; i += 512) ((float*)hl)[i] = 0.f;

  float4 hreg[4];  // [bb] over jj : this thread's owned h values
  float4 z0a[4];   // [bb] over zz : z0 accumulator (pmat==1 threads)
  hreg[0]=hreg[1]=hreg[2]=hreg[3]=make_float4(0.f,0.f,0.f,0.f);
  z0a[0]=z0a[1]=z0a[2]=z0a[3]=make_float4(0.f,0.f,0.f,0.f);

  for (int it = 0; it < 64; ++it) {
    const int s = d ? (63-it) : it;
    const float a_s = bnac[s], c_s = bnac[64+s];

    __syncthreads();                              // B0: prev readers of Fl/hl done
    for (int bb = wid; bb < 64; bb += 8) {        // stage Fl (coalesced global rows)
      const float* src = feats + (size_t)(b0+bb)*4160 + s*65;
      Fl[lane][bb] = a_s * src[lane];
      if (lane == 0) Fl[64][bb] = a_s * src[64];
    }
    __syncthreads();                              // B1: Fl (and prev h) visible

    float4 aR[4], aZ[4], aN1[4], aN2[4];          // [bb] over jj
    #pragma unroll
    for (int q=0;q<4;++q){ aR[q]=make_float4(0.f,0.f,0.f,0.f); aZ[q]=aR[q]; aN1[q]=aR[q]; aN2[q]=aR[q]; }

    #pragma unroll 4
    for (int k = 0; k < 65; ++k) {                // input transform (K=65)
      const float4 av = *(const float4*)&Fl[k][4*bg];
      const float* wr = wihtd + k*384 + 4*jg;
      const float4 w0 = *(const float4*)wr;
      const float4 w1 = *(const float4*)(wr+128);
      const float4 w2 = *(const float4*)(wr+256);
      #pragma unroll
      for (int q=0;q<4;++q) {
        const float a = vget(av,q);
        fma4(aR[q], a, w0); fma4(aZ[q], a, w1); fma4(aN1[q], a, w2);
      }
    }
    #pragma unroll 4
    for (int k = 0; k < 128; ++k) {               // recurrent (K=128)
      const float4 av = *(const float4*)&hl[k][4*bg];
      const float* wr = whhtd + k*384 + 4*jg;
      const float4 w0 = *(const float4*)wr;
      const float4 w1 = *(const float4*)(wr+128);
      const float4 w2 = *(const float4*)(wr+256);
      #pragma unroll
      for (int q=0;q<4;++q) {
        const float a = vget(av,q);
        fma4(aR[q], a, w0); fma4(aZ[q], a, w1); fma4(aN2[q], a, w2);
      }
    }
    // gates (PyTorch GRU): r=sig(xr+hr) z=sig(xz+hz) n=tanh(xn + r*hn)
    #pragma unroll
    for (int jj=0;jj<4;++jj) {
      const int j = 4*jg + jj;
      const float cr  = c_s*RS[j]     + BI[j]     + BH[j];
      const float cz  = c_s*RS[128+j] + BI[128+j] + BH[128+j];
      const float cn  = c_s*RS[256+j] + BI[256+j];
      const float bhn = BH[256+j];
      #pragma unroll
      for (int q=0;q<4;++q) {
        const float r = 1.f/(1.f + __expf(-(vget(aR[q],jj) + cr)));
        const float z = 1.f/(1.f + __expf(-(vget(aZ[q],jj) + cz)));
        const float pre = vget(aN1[q],jj) + cn + r*(vget(aN2[q],jj) + bhn);
        const float ax = fabsf(pre);
        const float e  = __expf(-2.f*ax);
        const float n  = copysignf((1.f-e)/(1.f+e), pre);
        ((float*)&hreg[q])[jj] = (1.f - z)*n + z*vget(hreg[q],jj);
      }
    }
    __syncthreads();                              // B2: all reads of old h done
    #pragma unroll
    for (int jj=0;jj<4;++jj) {
      const float4 hv = make_float4(vget(hreg[0],jj), vget(hreg[1],jj),
                                    vget(hreg[2],jj), vget(hreg[3],jj));
      *(float4*)&hl[4*jg+jj][4*bg] = hv;
    }
    __syncthreads();                              // B3: new h visible
    // projections: pmat==0 -> w_x[b,s,:] store; pmat==1 -> z0 += wz*xhat
    float4 pv[4];
    pv[0]=pv[1]=pv[2]=pv[3]=make_float4(0.f,0.f,0.f,0.f);
    const float* Wt = (pmat ? wztd : wxtd) + 4*pzg;
    #pragma unroll 4
    for (int k=0;k<128;++k) {
      const float4 hv = *(const float4*)&hl[k][4*pbg];
      const float4 wv = *(const float4*)(Wt + k*64);
      #pragma unroll
      for (int q=0;q<4;++q) fma4(pv[q], vget(hv,q), wv);
    }
    if (pmat == 0) {
      #pragma unroll
      for (int q=0;q<4;++q)
        *(float4*)&wxo[((size_t)(b0 + 4*pbg + q)*64 + s)*64 + 4*pzg] = pv[q];
    } else {
      #pragma unroll
      for (int q=0;q<4;++q) {
        const float xh = 2.f*xraw[(b0 + 4*pbg + q)*64 + s] - 3.f;  // 2x - 2^RATE + 1
        fma4(z0a[q], xh, pv[q]);
      }
    }
  }
  if (pmat == 1) {
    #pragma unroll
    for (int q=0;q<4;++q)
      *(float4*)&z0o[(size_t)(b0 + 4*pbg + q)*64 + 4*pzg] = z0a[q];
  }
}

// ---------------------------------------------------------------------------
// K4: per-batch GD loop + output:  whhw = wx^T (HtH wx); 10 iters; out = wx z
// ---------------------------------------------------------------------------
__global__ __launch_bounds__(256) void k_gd(
    const float* __restrict__ feats, const float* __restrict__ wxf, const float* __restrict__ wxb,
    const float* __restrict__ z0f, const float* __restrict__ z0b, float* __restrict__ out)
{
  __shared__ __align__(16) float wx[64][68];   // [s][z]
  __shared__ __align__(16) float t1[64][68];   // HtH @ wx  [t][z]
  __shared__ __align__(16) float ww[64][68];   // whhw [zi][zj]
  __shared__ float hty[64], wh[64], zv[64];
  const int b = blockIdx.x;
  const int tid = threadIdx.x;
  const float* fb = feats + (size_t)b*4160;
  for (int i = tid; i < 4096; i += 256)
    wx[i>>6][i&63] = wxf[(size_t)b*4096 + i] + wxb[(size_t)b*4096 + i];
  if (tid < 64) hty[tid] = fb[tid*65+64];
  __syncthreads();
  const int zq = tid & 15, tq = tid >> 4;
  #pragma unroll
  for (int tt=0; tt<4; ++tt) {                 // t1 = HtH @ wx
    const int t = 4*tq + tt;
    const float* hr = fb + t*65;
    float4 a = make_float4(0.f,0.f,0.f,0.f);
    for (int u=0; u<64; ++u) fma4(a, hr[u], *(const float4*)&wx[u][4*zq]);
    *(float4*)&t1[t][4*zq] = a;
  }
  __syncthreads();
  #pragma unroll
  for (int ii=0; ii<4; ++ii) {                 // ww = wx^T @ t1
    const int zi = 4*tq + ii;
    float4 a = make_float4(0.f,0.f,0.f,0.f);
    for (int t=0; t<64; ++t) fma4(a, wx[t][zi], *(const float4*)&t1[t][4*zq]);
    *(float4*)&ww[zi][4*zq] = a;
  }
  if (tid < 64) {                              // wxt_hty and z0
    float acc = 0.f;
    for (int t=0;t<64;++t) acc += wx[t][tid]*hty[t];
    wh[tid] = acc;
    zv[tid] = z0f[(size_t)b*64+tid] + z0b[(size_t)b*64+tid];
  }
  __syncthreads();
  for (int itr=0; itr<10; ++itr) {             // z += 2e-6*(wxt_hty - ww@z)
    float nz = 0.f;
    if (tid < 64) {
      float mv = 0.f;
      for (int k2=0;k2<64;++k2) mv += ww[tid][k2]*zv[k2];
      nz = zv[tid] + 2e-6f*(wh[tid] - mv);
    }
    __syncthreads();
    if (tid < 64) zv[tid] = nz;
    __syncthreads();
  }
  if (tid < 64) {                              // out = wx @ z
    float o = 0.f;
    for (int z2=0;z2<64;++z2) o += wx[tid][z2]*zv[z2];
    out[(size_t)b*64 + tid] = o;
  }
}

// ---------------------------------------------------------------------------
extern "C" void kernel_launch(void* const* d_in, const int* in_sizes, int n_in,
                              void* d_out, int out_size, void* d_ws, size_t ws_size,
                              hipStream_t stream)
{
  const float* y    = (const float*)d_in[0];
  const float* Hm   = (const float*)d_in[1];
  const float* xraw = (const float*)d_in[2];
  const float* wih  = (const float*)d_in[3];
  const float* whh  = (const float*)d_in[4];
  const float* bih  = (const float*)d_in[5];
  const float* bhh  = (const float*)d_in[6];
  const float* Wz   = (const float*)d_in[7];
  const float* Wx   = (const float*)d_in[8];
  const float* gam  = (const float*)d_in[9];
  const float* bet  = (const float*)d_in[10];
  float* out = (float*)d_out;
  float* ws  = (float*)d_ws;

  // ws layout (floats); total ~102.42M floats (~410 MB)
  float* feats = ws;                       // 8192*64*65   = 34,078,720
  float* wxf   = feats + 34078720ull;      // 8192*64*64   = 33,554,432
  float* wxb   = wxf   + 33554432ull;      // 33,554,432
  float* z0f   = wxb   + 33554432ull;      // 524,288
  float* z0b   = z0f   + 524288ull;        // 524,288
  float* wiht  = z0b   + 524288ull;        // 49,920
  float* whht  = wiht  + 49920ull;         // 98,304
  float* wzt   = whht  + 98304ull;         // 16,384
  float* wxt   = wzt   + 16384ull;         // 16,384
  float* rows  = wxt   + 16384ull;         // 768
  float* bnacc = rows  + 768ull;           // 2,048 (spaced x16)
  float* bnac  = bnacc + 2048ull;          // 128  (a[64], c[64])

  hipMemsetAsync(bnacc, 0, 2048*sizeof(float), stream);
  k_feats<<<8192, 256, 0, stream>>>(Hm, y, feats, bnacc);
  k_prep <<<384, 256, 0, stream>>>(wih, whh, Wz, Wx, wiht, whht, wzt, wxt, rows);
  k_bnfin<<<1, 64, 0, stream>>>(bnacc, gam, bet, bnac);
  k_scan <<<256, 512, 0, stream>>>(feats, xraw, wiht, whht, wxt, wzt,
                                   bih, bhh, rows, bnac, wxf, z0f);
  k_gd   <<<8192, 256, 0, stream>>>(feats, wxf, wxb, z0f, z0b, out);
}